// Round 1
// baseline (233.675 us; speedup 1.0000x reference)
//
#include <hip/hip_runtime.h>
#include <hip/hip_bf16.h>
#include <stdint.h>

// ---------------------------------------------------------------------------
// MemoryBank retrieve: O = softmax(q_n . k_n^T) @ keys_raw
//   N=65536, K=4096, D=128.  Scores in [-1,1] (unit vectors, beta=1) -> plain
//   exp accumulation (num, den), no online-softmax rescaling needed.
// ws layout: [0,16MB) q_n bf16 [N][128]; [+0,1MB) Kn_sw bf16 [K][128] chunk-
// XOR-swizzled; [+1MB) Vt_sw bf16 [128][K] (raw keys, transposed, swizzled).
// ---------------------------------------------------------------------------

typedef __attribute__((ext_vector_type(8))) short bf16x8;   // 8 bf16 = 4 VGPRs
typedef __attribute__((ext_vector_type(4))) float f32x4;

#define MFMA16(a, b, c) __builtin_amdgcn_mfma_f32_16x16x32_bf16(a, b, c, 0, 0, 0)

// async global->LDS, 16B per lane; LDS dest = wave-uniform base + lane*16
#define ASYNC_CP16(gsrc, ldst)                                                  \
  __builtin_amdgcn_global_load_lds(                                             \
      (const __attribute__((address_space(1))) void*)(gsrc),                    \
      (__attribute__((address_space(3))) void*)(ldst), 16, 0, 0)

__device__ __forceinline__ unsigned short f2bf(float x) {
  union { float f; unsigned int u; } v; v.f = x;
  unsigned int r = v.u + 0x7fffu + ((v.u >> 16) & 1u);   // RNE, no NaN inputs here
  return (unsigned short)(r >> 16);
}

// --------------------------- kernel A: normalize Q -> bf16 ------------------
__global__ __launch_bounds__(256) void norm_q(const float* __restrict__ q,
                                              unsigned int* __restrict__ qn, int N) {
  const int wave = threadIdx.x >> 6, lane = threadIdx.x & 63;
  const int row = blockIdx.x * 4 + wave;
  const float2 v = ((const float2*)(q + (size_t)row * 128))[lane];
  float ss = v.x * v.x + v.y * v.y;
#pragma unroll
  for (int off = 32; off; off >>= 1) ss += __shfl_xor(ss, off);
  const float s = ss > 0.f ? rsqrtf(ss) : 0.f;   // ||q|| >> 1e-12 in practice
  const unsigned int w =
      (unsigned int)f2bf(v.x * s) | ((unsigned int)f2bf(v.y * s) << 16);
  qn[(size_t)row * 64 + lane] = w;
}

// ------------------ kernel B: keys -> Kn_sw (normalized) + Vt_sw (raw) ------
// Kn_sw[key]: 16 chunks of 16B; logical chunk j stored at j ^ (key & 15).
// Vt_sw[d]:   per 64-key tile, 8 chunks of 16B; logical chunk j at j ^ (d & 7).
__global__ __launch_bounds__(256) void prep_k(const float* __restrict__ k,
                                              unsigned int* __restrict__ knsw,
                                              unsigned short* __restrict__ vtsw, int K) {
  const int wave = threadIdx.x >> 6, lane = threadIdx.x & 63;
  const int key = blockIdx.x * 4 + wave;
  const float2 v = ((const float2*)(k + (size_t)key * 128))[lane];
  float ss = v.x * v.x + v.y * v.y;
#pragma unroll
  for (int off = 32; off; off >>= 1) ss += __shfl_xor(ss, off);
  const float s = ss > 0.f ? rsqrtf(ss) : 0.f;
  // normalized keys, swizzled row-major [K][128]
  const unsigned int w =
      (unsigned int)f2bf(v.x * s) | ((unsigned int)f2bf(v.y * s) << 16);
  const int j = lane >> 2;                 // logical 16B chunk (4 dwords each)
  const int pj = j ^ (key & 15);
  knsw[(size_t)key * 64 + pj * 4 + (lane & 3)] = w;
  // raw keys, transposed [128][K], bf16, per-64-key-tile swizzle
  const int t = key & 63, k0 = key & ~63;
  const int d0 = 2 * lane, d1 = 2 * lane + 1;
  vtsw[(size_t)d0 * K + k0 + (((t >> 3) ^ (d0 & 7)) << 3) + (t & 7)] = f2bf(v.x);
  vtsw[(size_t)d1 * K + k0 + (((t >> 3) ^ (d1 & 7)) << 3) + (t & 7)] = f2bf(v.y);
}

// --------------------------- kernel C: fused attention ----------------------
// 256 thr = 4 waves; wave owns 32 query rows (mb=2 blocks of 16).
// Per iter: stage Kn tile [64][128] + Vt tile [128][64] (bf16) via
// global_load_lds; S = Q.Kn^T (16x16x32 MFMA); P=exp(S) -> per-wave LDS
// (row stride 72 elem = 144B: 16B-aligned, conflict-free-ish); O += P.V.
__global__ __launch_bounds__(256, 2) void attn_main(
    const unsigned int* __restrict__ qn, const char* __restrict__ knsw,
    const char* __restrict__ vtsw, float* __restrict__ out, int N, int K) {
  __shared__ __align__(16) char smem[16384 + 16384 + 4 * 32 * 72 * 2];
  char* sKn = smem;                     // [64 keys][256B], swizzled image
  char* sVt = smem + 16384;             // [128 d][128B],  swizzled image
  const int tid = threadIdx.x;
  const int wave = tid >> 6, lane = tid & 63;
  const int g = lane >> 4, c = lane & 15;
  char* sP = smem + 32768 + wave * 4608;   // per-wave P: 32 rows x 144B
  const int rowbase = blockIdx.x * 128 + wave * 32;

  // Q A-fragments resident in VGPRs: A[m=lane&15][k=g*8+j (+32*ks)]
  bf16x8 qf[2][4];
#pragma unroll
  for (int mb = 0; mb < 2; ++mb)
#pragma unroll
    for (int ks = 0; ks < 4; ++ks)
      qf[mb][ks] = *(const bf16x8*)((const char*)qn +
                    (size_t)(rowbase + mb * 16 + c) * 256 + ks * 64 + g * 16);

  f32x4 acc[2][8];
  float den[2][4];
#pragma unroll
  for (int mb = 0; mb < 2; ++mb) {
#pragma unroll
    for (int nb = 0; nb < 8; ++nb) acc[mb][nb] = (f32x4){0.f, 0.f, 0.f, 0.f};
#pragma unroll
    for (int r = 0; r < 4; ++r) den[mb][r] = 0.f;
  }

  const int nIter = K >> 6;
  const size_t vstride = (size_t)K * 2;

  for (int it = 0; it < nIter; ++it) {
    const int kt = it << 6;
    __syncthreads();   // previous tile's LDS reads done
    // stage Kn tile: 16KB = 16 chunks of 1KB; wave w does chunks 4w..4w+3
#pragma unroll
    for (int i = 0; i < 4; ++i)
      ASYNC_CP16(knsw + (size_t)kt * 256 + wave * 4096 + i * 1024 + lane * 16,
                 sKn + wave * 4096 + i * 1024);
    // stage Vt tile: chunk covers 8 d-rows x 128B
#pragma unroll
    for (int i = 0; i < 4; ++i)
      ASYNC_CP16(vtsw + (size_t)(wave * 32 + i * 8 + (lane >> 3)) * vstride +
                     (size_t)kt * 2 + (lane & 7) * 16,
                 sVt + wave * 4096 + i * 1024);
    __syncthreads();   // staging complete (compiler emits vmcnt(0) drain)

    // ---- S = Qn . Kn^T per 16-key block; P = exp(S) -> sP -----------------
#pragma unroll
    for (int nb = 0; nb < 4; ++nb) {
      f32x4 s0 = {0.f, 0.f, 0.f, 0.f}, s1 = {0.f, 0.f, 0.f, 0.f};
#pragma unroll
      for (int ks = 0; ks < 4; ++ks) {
        // B[k=d][n=key]: lane holds key=nb*16+c, d = (ks*4+g)*8 + j
        const bf16x8 kf = *(const bf16x8*)(sKn + (nb * 16 + c) * 256 +
                                           (((ks * 4 + g) ^ c) << 4));
        s0 = MFMA16(qf[0][ks], kf, s0);
        s1 = MFMA16(qf[1][ks], kf, s1);
      }
#pragma unroll
      for (int r = 0; r < 4; ++r) {
        const float e0 = __builtin_amdgcn_exp2f(s0[r] * 1.44269504f);
        const float e1 = __builtin_amdgcn_exp2f(s1[r] * 1.44269504f);
        den[0][r] += e0;
        den[1][r] += e1;
        // C layout: row=(g*4+r), col=nb*16+c
        ((unsigned short*)sP)[(g * 4 + r) * 72 + nb * 16 + c] = f2bf(e0);
        ((unsigned short*)sP)[(16 + g * 4 + r) * 72 + nb * 16 + c] = f2bf(e1);
      }
    }

    // ---- O += P . V  (per-wave P; same-wave LDS ordering via waitcnt) -----
#pragma unroll
    for (int ks2 = 0; ks2 < 2; ++ks2) {
      const bf16x8 p0 = *(const bf16x8*)(sP + c * 144 + ks2 * 64 + g * 16);
      const bf16x8 p1 = *(const bf16x8*)(sP + (16 + c) * 144 + ks2 * 64 + g * 16);
#pragma unroll
      for (int nb = 0; nb < 8; ++nb) {
        // B[k=key][n=d]: lane holds d=nb*16+c, key = (ks2*4+g)*8 + j
        const bf16x8 vf = *(const bf16x8*)(sVt + (nb * 16 + c) * 128 +
                                           ((((ks2 * 4 + g) ^ (c & 7))) << 4));
        acc[0][nb] = MFMA16(p0, vf, acc[0][nb]);
        acc[1][nb] = MFMA16(p1, vf, acc[1][nb]);
      }
    }
  }

  // den: sum over the 16 column-lanes (same g-group holds same rows)
#pragma unroll
  for (int mb = 0; mb < 2; ++mb)
#pragma unroll
    for (int r = 0; r < 4; ++r) {
      float d = den[mb][r];
      d += __shfl_xor(d, 1);
      d += __shfl_xor(d, 2);
      d += __shfl_xor(d, 4);
      d += __shfl_xor(d, 8);
      den[mb][r] = 1.0f / d;
    }

#pragma unroll
  for (int mb = 0; mb < 2; ++mb)
#pragma unroll
    for (int nb = 0; nb < 8; ++nb)
#pragma unroll
      for (int r = 0; r < 4; ++r)
        out[(size_t)(rowbase + mb * 16 + g * 4 + r) * 128 + nb * 16 + c] =
            acc[mb][nb][r] * den[mb][r];
}

// ---------------------------------------------------------------------------
extern "C" void kernel_launch(void* const* d_in, const int* in_sizes, int n_in,
                              void* d_out, int out_size, void* d_ws, size_t ws_size,
                              hipStream_t stream) {
  const float* q = (const float*)d_in[0];
  const float* k = (const float*)d_in[1];
  const int N = in_sizes[0] / 128;   // 65536
  const int K = in_sizes[1] / 128;   // 4096
  char* ws = (char*)d_ws;
  // ws usage: N*256 (q_n) + K*256 (Kn_sw) + K*256 (Vt_sw) = 18 MB
  unsigned int* qn = (unsigned int*)ws;
  unsigned int* knsw = (unsigned int*)(ws + (size_t)N * 256);
  unsigned short* vtsw = (unsigned short*)(ws + (size_t)N * 256 + (size_t)K * 256);
  float* out = (float*)d_out;

  norm_q<<<dim3(N / 4), dim3(256), 0, stream>>>(q, qn, N);
  prep_k<<<dim3(K / 4), dim3(256), 0, stream>>>(k, knsw, vtsw, K);
  attn_main<<<dim3(N / 128), dim3(256), 0, stream>>>(qn, (const char*)knsw,
                                                     (const char*)vtsw, out, N, K);
}